// Round 8
// baseline (258.150 us; speedup 1.0000x reference)
//
#include <hip/hip_runtime.h>

// ROIAlign forward (PH=PW=7, SCALE=0.25, SR=2, ALIGNED=true)
//   input [4,256,200,200] fp32 NCHW, rois [512,5], out [512,256,7,7] fp32
//
// R8 design: R7 (async global->LDS staging, 257.4us measured) + ONE change:
// STRIP 50->40 (NSTRIP=5, STAGE_ROWS=46, LDS 44.8->36.8 KB) -> 4 blocks/CU
// (32 waves = occupancy cap). Mechanism: with async staging, the only
// latency-hiding across the per-block vmcnt(0) barrier drain is OTHER
// resident blocks' compute; depth 3->4 increases that overlap.
//   - R5 post-mortem (272.4): geometry tables hurt (cold ws reads) — keep
//     inline geometry recompute (L1-hot rois, measured-best).
//   - R6 post-mortem (274.9): LDS tap pairing no help — keep simple taps.
//   - R7 post-mortem (257.4): global_load_lds staging = -4.8us WIN — kept.
//   - Cover proof: binh <= 64/7 => tap rows <= lo0+6; STAGE_ROWS=STRIP+6=46
//     covers lo0 in [40s, 40s+39]. Edge clamp (row 199) only when
//     lo0 >= 194 -> bucket 4 -> staged. Bucket = lo0/40, lo0 = min row.
//   - ws layout: counters [0..31] (20 used), lists at ws+32.
// Fixed harness overhead ~160us (640MB ws poison ~100us + input restore +
// out poison) is untouchable.

#define R_PH 7
#define R_PW 7
#define R_SR 2
#define R_SCALE 0.25f
#define R_C 256
#define R_H 200
#define R_W 200
#define R_HW (R_H * R_W)
#define STRIP 40
#define NSTRIP 5
#define STAGE_ROWS 46   // STRIP + 6
#define NBUCKET (NSTRIP * 4)

__device__ __forceinline__ void axis_sample(float start, float bin, int p, int s, int size,
                                            int& lo, int& hi, float& wlo, float& whi) {
    // coord = start + p*bin + (s+0.5)*bin/SR   (same grouping as reference)
    float coord = (start + (float)p * bin) + ((float)s + 0.5f) * bin * (1.0f / R_SR);
    bool valid = (coord >= -1.0f) && (coord <= (float)size);
    float c = fmaxf(coord, 0.0f);
    int lo_raw = (int)floorf(c);
    bool at_edge = lo_raw >= size - 1;
    lo = at_edge ? size - 1 : lo_raw;
    hi = at_edge ? size - 1 : lo_raw + 1;
    float cv = at_edge ? (float)(size - 1) : c;
    float frac = cv - (float)lo;          // weight toward hi
    whi = valid ? frac : 0.0f;
    wlo = valid ? (1.0f - frac) : 0.0f;
}

// ---------- Pre-kernel: build per-(batch,strip) lists of (roi, ph) ----------
// ws layout: int cnt[32] (20 used); int lists[20][N*7] starting at ws+32
__global__ void __launch_bounds__(512)
build_lists(const float* __restrict__ rois, int N, int* __restrict__ ws) {
    __shared__ int lcnt[NBUCKET];
    int t = threadIdx.x;
    if (t < NBUCKET) lcnt[t] = 0;
    __syncthreads();
    int* lists = ws + 32;
    for (int n = t; n < N; n += 512) {
        const float* r = rois + (size_t)n * 5;
        int b = (int)r[0];
        float sy = r[2] * R_SCALE - 0.5f;
        float ey = r[4] * R_SCALE - 0.5f;
        float binh = (ey - sy) * (1.0f / R_PH);
        for (int ph = 0; ph < R_PH; ++ph) {
            int lo, hi; float wl, wh;
            axis_sample(sy, binh, ph, 0, R_H, lo, hi, wl, wh);  // s=0 lo == min row
            int bs = b * NSTRIP + lo / STRIP;                   // lo in [0,199]
            int pos = atomicAdd(&lcnt[bs], 1);
            lists[bs * (N * R_PH) + pos] = (n << 3) | ph;
        }
    }
    __syncthreads();
    if (t < NBUCKET) ws[t] = lcnt[t];
}

// ---------- Main: strip-LDS gather, async global->LDS staging ----------
// grid (C=256, B=4, NSTRIP=5), block 512, 36.8 KB LDS -> 4 blocks/CU
__global__ void __launch_bounds__(512)
roi_strip(const float* __restrict__ input,
          const float* __restrict__ rois,
          const int* __restrict__ ws, int N,
          float* __restrict__ out) {
    __shared__ float pl[STAGE_ROWS * R_W];   // 36800 B
    int c = blockIdx.x;
    int b = blockIdx.y;
    int s = blockIdx.z;

    int m = ws[b * NSTRIP + s];
    if (m == 0) return;

    int r0 = s * STRIP;
    int nrows = min(STAGE_ROWS, R_H - r0);

    // Async direct global->LDS staging (no VGPR round-trip) — R7 win, kept.
    // Linear pattern: float4 #i -> LDS bytes [16i,16i+16) — matches the
    // hardware's wave-uniform-base + lane*16 LDS addressing.
    const float* src = input + (size_t)(b * R_C + c) * R_HW + r0 * R_W;
    int nf4 = nrows * (R_W / 4);
    int tid = threadIdx.x;
    for (int base = 0; base < nf4; base += 512) {
        int i = base + tid;
        if (i < nf4) {
            __builtin_amdgcn_global_load_lds(
                (const __attribute__((address_space(1))) void*)(src + (size_t)i * 4),
                (__attribute__((address_space(3))) void*)(pl + (size_t)i * 4),
                16, 0, 0);
        }
    }

    const int* list = ws + 32 + (b * NSTRIP + s) * (N * R_PH);
    __syncthreads();   // drains vmcnt(0): all global_load_lds complete

    int total = m * R_PW;
    for (int i = threadIdx.x; i < total; i += 512) {
        int e  = i / R_PW;
        int pw = i - e * R_PW;
        int code = list[e];
        int n  = code >> 3;
        int ph = code & 7;
        const float* r = rois + (size_t)n * 5;
        float sx = r[1] * R_SCALE - 0.5f;
        float sy = r[2] * R_SCALE - 0.5f;
        float ex = r[3] * R_SCALE - 0.5f;
        float ey = r[4] * R_SCALE - 0.5f;
        float binw = (ex - sx) * (1.0f / R_PW);
        float binh = (ey - sy) * (1.0f / R_PH);

        int   ylo[R_SR], yhi[R_SR], xlo[R_SR], xhi[R_SR];
        float wyl[R_SR], wyh[R_SR], wxl[R_SR], wxh[R_SR];
#pragma unroll
        for (int q = 0; q < R_SR; ++q) {
            axis_sample(sy, binh, ph, q, R_H, ylo[q], yhi[q], wyl[q], wyh[q]);
            axis_sample(sx, binw, pw, q, R_W, xlo[q], xhi[q], wxl[q], wxh[q]);
        }

        float acc = 0.0f;
#pragma unroll
        for (int ys = 0; ys < R_SR; ++ys) {
            const float* rlo = pl + (ylo[ys] - r0) * R_W;
            const float* rhi = pl + (yhi[ys] - r0) * R_W;
#pragma unroll
            for (int xs = 0; xs < R_SR; ++xs) {
                acc += wyl[ys] * (wxl[xs] * rlo[xlo[xs]] + wxh[xs] * rlo[xhi[xs]])
                     + wyh[ys] * (wxl[xs] * rhi[xlo[xs]] + wxh[xs] * rhi[xhi[xs]]);
            }
        }
        out[(size_t)(n * R_C + c) * 49 + ph * R_PW + pw] = acc * 0.25f;
    }
}

// ---------- Fallback: single-pass kernel (if ws too small) ----------
__global__ void __launch_bounds__(256)
roi_align_fwd(const float* __restrict__ input,
              const float* __restrict__ rois,
              float* __restrict__ out, int total) {
    int idx = blockIdx.x * blockDim.x + threadIdx.x;
    if (idx >= total) return;
    int pw = idx % R_PW;
    int ph = (idx / R_PW) % R_PH;
    int c  = (idx / (R_PW * R_PH)) % R_C;
    int n  = idx / (R_PW * R_PH * R_C);
    const float* r = rois + (size_t)n * 5;
    int   b  = (int)r[0];
    float sx = r[1] * R_SCALE - 0.5f;
    float sy = r[2] * R_SCALE - 0.5f;
    float ex = r[3] * R_SCALE - 0.5f;
    float ey = r[4] * R_SCALE - 0.5f;
    float bin_w = (ex - sx) * (1.0f / R_PW);
    float bin_h = (ey - sy) * (1.0f / R_PH);
    const float* plane = input + (size_t)(b * R_C + c) * R_HW;
    int   ylo[R_SR], yhi[R_SR], xlo[R_SR], xhi[R_SR];
    float wylo[R_SR], wyhi[R_SR], wxlo[R_SR], wxhi[R_SR];
#pragma unroll
    for (int s = 0; s < R_SR; ++s) {
        axis_sample(sy, bin_h, ph, s, R_H, ylo[s], yhi[s], wylo[s], wyhi[s]);
        axis_sample(sx, bin_w, pw, s, R_W, xlo[s], xhi[s], wxlo[s], wxhi[s]);
    }
    float acc = 0.0f;
#pragma unroll
    for (int ys = 0; ys < R_SR; ++ys) {
        const float* row_lo = plane + ylo[ys] * R_W;
        const float* row_hi = plane + yhi[ys] * R_W;
#pragma unroll
        for (int xs = 0; xs < R_SR; ++xs) {
            acc += wylo[ys] * (wxlo[xs] * row_lo[xlo[xs]] + wxhi[xs] * row_lo[xhi[xs]])
                 + wyhi[ys] * (wxlo[xs] * row_hi[xlo[xs]] + wxhi[xs] * row_hi[xhi[xs]]);
        }
    }
    out[idx] = acc * (1.0f / (R_SR * R_SR));
}

extern "C" void kernel_launch(void* const* d_in, const int* in_sizes, int n_in,
                              void* d_out, int out_size, void* d_ws, size_t ws_size,
                              hipStream_t stream) {
    const float* input = (const float*)d_in[0];
    const float* rois  = (const float*)d_in[1];
    float* out = (float*)d_out;
    int N = in_sizes[1] / 5;

    size_t ws_needed = (size_t)(32 + NBUCKET * N * R_PH) * sizeof(int);  // ~290 KB @ N=512
    if (ws_size >= ws_needed) {
        int* ws = (int*)d_ws;
        build_lists<<<1, 512, 0, stream>>>(rois, N, ws);
        dim3 grid(R_C, 4, NSTRIP);          // c, b, strip
        roi_strip<<<grid, 512, 0, stream>>>(input, rois, ws, N, out);
    } else {
        int total = out_size;
        roi_align_fwd<<<(total + 255) / 256, 256, 0, stream>>>(input, rois, out, total);
    }
}

// Round 9
// 252.997 us; speedup vs baseline: 1.0204x; 1.0204x over previous
//
#include <hip/hip_runtime.h>

// ROIAlign forward (PH=PW=7, SCALE=0.25, SR=2, ALIGNED=true)
//   input [4,256,200,200] fp32 NCHW, rois [512,5], out [512,256,7,7] fp32
//
// R9 design: FUSED single-dispatch strip-LDS gather.
//   Ladder: R4 262.2 (strip-LDS base) -> R5 272.4 (geom tables: HURT) ->
//   R6 274.9 (tap pairing: null) -> R7 257.4 (async global_load_lds: WIN)
//   -> R8 258.2 (4 blocks/CU: null).
//   Remaining structural overhead: serial 1-block build_lists (~3-5us whole-
//   GPU idle) + kernel-boundary drain + cold-d_ws list reads (640MB poison
//   evicts ws every iteration). R9 removes all three:
//     - each block (c,b,s) scans the rois itself and compacts its (n,ph)
//       list into LDS. Roi fields are preloaded to registers BEFORE the
//       async staging issue, so the scan is VALU+DS only and runs entirely
//       in the staging-latency shadow (no vmcnt dependency).
//     - single dispatch, no workspace use at all.
//   Phase order (vmcnt discipline):
//     (1) lcnt=0; preload roi[tid] fields -> regs
//     (2) __syncthreads  (drains only the tiny roi loads; staging not issued)
//     (3) issue ~5 global_load_lds_dwordx4 per thread (fire-and-forget)
//     (4) scan: geometry from regs, ds-append (n<<3|ph) if bucket==(b,s)
//     (5) __syncthreads  (drains staging vmcnt(0) + list lgkm)
//     (6) per-item gather: inline geometry (R5: tables hurt), 16 LDS taps
//   Cover proof (unchanged): binh <= 64/7 -> tap rows <= lo0+6;
//   STAGE_ROWS=STRIP+6=56 covers lo0 in [50s,50s+49]; edge clamp (row 199)
//   only when lo0 >= 194 -> strip 3 -> staged. Bucket = lo0/50, lo0=min row.
//   LDS: 44800 (plane) + 7168 (list, worst case N*7=3584 ushort) + 4 = 52KB
//   -> 3 blocks/CU (R8 showed 3-vs-4 is null).
// Fixed harness overhead ~155us (640MB ws poison ~100us + input restore +
// out poison) is untouchable.

#define R_PH 7
#define R_PW 7
#define R_SR 2
#define R_SCALE 0.25f
#define R_C 256
#define R_H 200
#define R_W 200
#define R_HW (R_H * R_W)
#define STRIP 50
#define NSTRIP 4
#define STAGE_ROWS 56   // STRIP + 6
#define MAXROI 512      // fused path supports N <= MAXROI (harness: N=512)
#define MAXE (MAXROI * R_PH)

__device__ __forceinline__ void axis_sample(float start, float bin, int p, int s, int size,
                                            int& lo, int& hi, float& wlo, float& whi) {
    // coord = start + p*bin + (s+0.5)*bin/SR   (same grouping as reference)
    float coord = (start + (float)p * bin) + ((float)s + 0.5f) * bin * (1.0f / R_SR);
    bool valid = (coord >= -1.0f) && (coord <= (float)size);
    float c = fmaxf(coord, 0.0f);
    int lo_raw = (int)floorf(c);
    bool at_edge = lo_raw >= size - 1;
    lo = at_edge ? size - 1 : lo_raw;
    hi = at_edge ? size - 1 : lo_raw + 1;
    float cv = at_edge ? (float)(size - 1) : c;
    float frac = cv - (float)lo;          // weight toward hi
    whi = valid ? frac : 0.0f;
    wlo = valid ? (1.0f - frac) : 0.0f;
}

// ---------- Fused: scan + async stage + gather, one dispatch ----------
// grid (C=256, B=4, NSTRIP=4), block 512, 52 KB LDS -> 3 blocks/CU
__global__ void __launch_bounds__(512)
roi_fused(const float* __restrict__ input,
          const float* __restrict__ rois, int N,
          float* __restrict__ out) {
    __shared__ float pl[STAGE_ROWS * R_W];     // 44800 B
    __shared__ unsigned short lst[MAXE];       // 7168 B
    __shared__ int lcnt;
    int c = blockIdx.x;
    int b = blockIdx.y;
    int s = blockIdx.z;
    int tid = threadIdx.x;

    // (1) init + preload this thread's roi fields (before staging issue, so
    //     the scan below has no vmcnt dependency on the staging queue)
    if (tid == 0) lcnt = 0;
    float f0 = 0.f, f2 = 0.f, f4 = 0.f;
    if (tid < N) {
        const float* r = rois + (size_t)tid * 5;
        f0 = r[0]; f2 = r[2]; f4 = r[4];
    }
    __syncthreads();   // lcnt visible; drains only the tiny roi loads

    // (3) async direct global->LDS staging (R7 win): fire-and-forget,
    //     linear float4 #i -> LDS bytes [16i,16i+16)
    int r0 = s * STRIP;
    int nrows = min(STAGE_ROWS, R_H - r0);
    const float* src = input + (size_t)(b * R_C + c) * R_HW + r0 * R_W;
    int nf4 = nrows * (R_W / 4);
    for (int base = 0; base < nf4; base += 512) {
        int i = base + tid;
        if (i < nf4) {
            __builtin_amdgcn_global_load_lds(
                (const __attribute__((address_space(1))) void*)(src + (size_t)i * 4),
                (__attribute__((address_space(3))) void*)(pl + (size_t)i * 4),
                16, 0, 0);
        }
    }

    // (4) scan: build this block's (n,ph) list in LDS — overlaps staging.
    //     First pass uses preloaded regs (N<=512 in harness: loop runs once).
    for (int n = tid; n < N; n += 512) {
        float a0, a2, a4;
        if (n == tid) { a0 = f0; a2 = f2; a4 = f4; }
        else { const float* r = rois + (size_t)n * 5; a0 = r[0]; a2 = r[2]; a4 = r[4]; }
        if ((int)a0 == b) {
            float sy = a2 * R_SCALE - 0.5f;
            float ey = a4 * R_SCALE - 0.5f;
            float binh = (ey - sy) * (1.0f / R_PH);
            for (int ph = 0; ph < R_PH; ++ph) {
                int lo, hi; float wl, wh;
                axis_sample(sy, binh, ph, 0, R_H, lo, hi, wl, wh);  // s=0 lo == min row
                if (lo / STRIP == s) {
                    int pos = atomicAdd(&lcnt, 1);
                    lst[pos] = (unsigned short)((n << 3) | ph);
                }
            }
        }
    }

    __syncthreads();   // drains staging vmcnt(0) + list lgkm
    int m = lcnt;

    // (6) gather: inline geometry (R5 showed tables hurt), 16 LDS taps/item
    int total = m * R_PW;
    for (int i = tid; i < total; i += 512) {
        int e  = i / R_PW;
        int pw = i - e * R_PW;
        int code = lst[e];
        int n  = code >> 3;
        int ph = code & 7;
        const float* r = rois + (size_t)n * 5;
        float sx = r[1] * R_SCALE - 0.5f;
        float sy = r[2] * R_SCALE - 0.5f;
        float ex = r[3] * R_SCALE - 0.5f;
        float ey = r[4] * R_SCALE - 0.5f;
        float binw = (ex - sx) * (1.0f / R_PW);
        float binh = (ey - sy) * (1.0f / R_PH);

        int   ylo[R_SR], yhi[R_SR], xlo[R_SR], xhi[R_SR];
        float wyl[R_SR], wyh[R_SR], wxl[R_SR], wxh[R_SR];
#pragma unroll
        for (int q = 0; q < R_SR; ++q) {
            axis_sample(sy, binh, ph, q, R_H, ylo[q], yhi[q], wyl[q], wyh[q]);
            axis_sample(sx, binw, pw, q, R_W, xlo[q], xhi[q], wxl[q], wxh[q]);
        }

        float acc = 0.0f;
#pragma unroll
        for (int ys = 0; ys < R_SR; ++ys) {
            const float* rlo = pl + (ylo[ys] - r0) * R_W;
            const float* rhi = pl + (yhi[ys] - r0) * R_W;
#pragma unroll
            for (int xs = 0; xs < R_SR; ++xs) {
                acc += wyl[ys] * (wxl[xs] * rlo[xlo[xs]] + wxh[xs] * rlo[xhi[xs]])
                     + wyh[ys] * (wxl[xs] * rhi[xlo[xs]] + wxh[xs] * rhi[xhi[xs]]);
            }
        }
        out[(size_t)(n * R_C + c) * 49 + ph * R_PW + pw] = acc * 0.25f;
    }
}

// ---------- Fallback: single-pass kernel (if N > MAXROI) ----------
__global__ void __launch_bounds__(256)
roi_align_fwd(const float* __restrict__ input,
              const float* __restrict__ rois,
              float* __restrict__ out, int total) {
    int idx = blockIdx.x * blockDim.x + threadIdx.x;
    if (idx >= total) return;
    int pw = idx % R_PW;
    int ph = (idx / R_PW) % R_PH;
    int c  = (idx / (R_PW * R_PH)) % R_C;
    int n  = idx / (R_PW * R_PH * R_C);
    const float* r = rois + (size_t)n * 5;
    int   b  = (int)r[0];
    float sx = r[1] * R_SCALE - 0.5f;
    float sy = r[2] * R_SCALE - 0.5f;
    float ex = r[3] * R_SCALE - 0.5f;
    float ey = r[4] * R_SCALE - 0.5f;
    float bin_w = (ex - sx) * (1.0f / R_PW);
    float bin_h = (ey - sy) * (1.0f / R_PH);
    const float* plane = input + (size_t)(b * R_C + c) * R_HW;
    int   ylo[R_SR], yhi[R_SR], xlo[R_SR], xhi[R_SR];
    float wylo[R_SR], wyhi[R_SR], wxlo[R_SR], wxhi[R_SR];
#pragma unroll
    for (int s = 0; s < R_SR; ++s) {
        axis_sample(sy, bin_h, ph, s, R_H, ylo[s], yhi[s], wylo[s], wyhi[s]);
        axis_sample(sx, bin_w, pw, s, R_W, xlo[s], xhi[s], wxlo[s], wxhi[s]);
    }
    float acc = 0.0f;
#pragma unroll
    for (int ys = 0; ys < R_SR; ++ys) {
        const float* row_lo = plane + ylo[ys] * R_W;
        const float* row_hi = plane + yhi[ys] * R_W;
#pragma unroll
        for (int xs = 0; xs < R_SR; ++xs) {
            acc += wylo[ys] * (wxlo[xs] * row_lo[xlo[xs]] + wxhi[xs] * row_lo[xhi[xs]])
                 + wyhi[ys] * (wxlo[xs] * row_hi[xlo[xs]] + wxhi[xs] * row_hi[xhi[xs]]);
        }
    }
    out[idx] = acc * (1.0f / (R_SR * R_SR));
}

extern "C" void kernel_launch(void* const* d_in, const int* in_sizes, int n_in,
                              void* d_out, int out_size, void* d_ws, size_t ws_size,
                              hipStream_t stream) {
    const float* input = (const float*)d_in[0];
    const float* rois  = (const float*)d_in[1];
    float* out = (float*)d_out;
    int N = in_sizes[1] / 5;

    if (N <= MAXROI) {
        dim3 grid(R_C, 4, NSTRIP);          // c, b, strip — single dispatch
        roi_fused<<<grid, 512, 0, stream>>>(input, rois, N, out);
    } else {
        int total = out_size;
        roi_align_fwd<<<(total + 255) / 256, 256, 0, stream>>>(input, rois, out, total);
    }
}